// Round 1
// baseline (529.760 us; speedup 1.0000x reference)
//
#include <hip/hip_runtime.h>

#define KP 40   // padded K stride (elems) for LDS weight tiles: 80 B rows -> conflict-free b128 reads

typedef __attribute__((ext_vector_type(8))) short bf16x8;
typedef __attribute__((ext_vector_type(16))) float f32x16;

union FragU { bf16x8 v; unsigned int u[4]; };

struct Wptrs { const float* p[16]; };

__device__ __forceinline__ unsigned int bfb(float f) {
  unsigned int u = __builtin_bit_cast(unsigned int, f);
  return (u + 0x7fffu + ((u >> 16) & 1u)) >> 16;   // RNE f32 -> bf16 bits
}
__device__ __forceinline__ unsigned int packbf(float a, float b) {
  return bfb(a) | (bfb(b) << 16);
}
__device__ __forceinline__ float silu_f(float x) {
  float e = __builtin_amdgcn_exp2f(-1.4426950408889634f * x);
  return x * __builtin_amdgcn_rcpf(1.0f + e);
}
__device__ __forceinline__ f32x16 zero16() {
  f32x16 z;
  #pragma unroll
  for (int i = 0; i < 16; ++i) z[i] = 0.0f;
  return z;
}
__device__ __forceinline__ bf16x8 ldsA(const unsigned short* s_w, int tile, int l31, int hi, int h) {
  return *(const bf16x8*)(s_w + (tile * 32 + l31) * KP + h * 16 + hi * 8);
}

// C layout (32x32x16): col p = lane&31, row j = (reg&3)+8*(reg>>2)+4*hi.
// Next-layer B frag: lane holds k = 8*hi+i (frag0: k 0..15 global, frag1: k 16..31).
// Exchange the two reg-quads the partner half-wave owns via shfl_xor(32).
__device__ __forceinline__ void transition(const f32x16& acc, int hi, bf16x8& b0, bf16x8& b1) {
  unsigned int P[8];
  #pragma unroll
  for (int t = 0; t < 8; ++t) {
    float a = silu_f(acc[2*t]);
    float b = silu_f(acc[2*t+1]);
    P[t] = packbf(a, b);
  }
  unsigned int Q[8];
  #pragma unroll
  for (int t = 0; t < 8; ++t) Q[t] = (unsigned int)__shfl_xor((int)P[t], 32, 64);
  FragU f0, f1;
  f0.u[0] = hi ? Q[2] : P[0];
  f0.u[1] = hi ? Q[3] : P[1];
  f0.u[2] = hi ? P[2] : Q[0];
  f0.u[3] = hi ? P[3] : Q[1];
  f1.u[0] = hi ? Q[6] : P[4];
  f1.u[1] = hi ? Q[7] : P[5];
  f1.u[2] = hi ? P[6] : Q[4];
  f1.u[3] = hi ? P[7] : Q[5];
  b0 = f0.v; b1 = f1.v;
}

template<int NL, int OFF>
__device__ __forceinline__ void phase(const float* __restrict__ rad, float* __restrict__ out,
    const float* __restrict__ w1, const float* __restrict__ w2,
    const float* __restrict__ w3, const float* __restrict__ w4,
    unsigned short* s_w, const unsigned short* s_perm,
    const int* s_cnt, const int* s_off, const int* s_gpre,
    int base, int tid)
{
  __syncthreads();                                   // prev phase done reading s_w
  for (int i = tid; i < 16*32*KP; i += 256) s_w[i] = 0;
  __syncthreads();                                   // zero before transposed fill
  // w1: (4, NL, 32) [s][k][j] -> tile s, Wt[j][k]
  for (int i = tid; i < 4*NL*32; i += 256) {
    int s = i / (NL*32); int r = i - s*(NL*32); int k = r >> 5; int j = r & 31;
    s_w[((0*4 + s)*32 + j)*KP + k] = (unsigned short)bfb(w1[i]);
  }
  // w2/w3: (4,32,32) [s][k][j] -> tiles 4+s / 8+s
  for (int i = tid; i < 4096; i += 256) {
    int s = i >> 10; int k = (i >> 5) & 31; int j = i & 31;
    s_w[((4 + s)*32 + j)*KP + k] = (unsigned short)bfb(w2[i]);
    s_w[((8 + s)*32 + j)*KP + k] = (unsigned short)bfb(w3[i]);
  }
  // w4: (4, 32, NL) [s][k][jo] -> tiles 12+s, Wt[jo][k]
  for (int i = tid; i < 4*32*NL; i += 256) {
    int s = i / (32*NL); int r = i - s*(32*NL); int k = r / NL; int jo = r - k*NL;
    s_w[((12 + s)*32 + jo)*KP + k] = (unsigned short)bfb(w4[i]);
  }
  __syncthreads();

  const int lane = tid & 63, wid = tid >> 6;
  const int l31 = lane & 31, hi = lane >> 5;
  const int Gtot = s_gpre[4];
  for (int g = wid; g < Gtot; g += 4) {
    int s = (g >= s_gpre[1]) + (g >= s_gpre[2]) + (g >= s_gpre[3]);
    int gi = g - s_gpre[s];
    int goff = s_off[s] + gi*32;
    int gcnt = s_cnt[s] - gi*32; if (gcnt > 32) gcnt = 32;
    int li = l31 < gcnt ? l31 : gcnt - 1;
    int row = base + (int)s_perm[goff + li];
    const float* rp = rad + (long)row * 72 + OFF;

    // layer-1 B frags straight from global: lane reads 8 contiguous floats of row p
    FragU bx0; FragU bx1;
    {
      int kl = hi * 8;
      float4 q0 = make_float4(0.f,0.f,0.f,0.f), q1 = q0;
      if (kl + 4 <= NL) q0 = *(const float4*)(rp + kl);
      if (kl + 8 <= NL) q1 = *(const float4*)(rp + kl + 4);
      bx0.u[0] = packbf(q0.x, q0.y); bx0.u[1] = packbf(q0.z, q0.w);
      bx0.u[2] = packbf(q1.x, q1.y); bx0.u[3] = packbf(q1.z, q1.w);
      if (NL > 16) {
        int k2 = 16 + hi * 8;
        float4 r0 = make_float4(0.f,0.f,0.f,0.f), r1 = r0;
        if (k2 + 4 <= NL) r0 = *(const float4*)(rp + k2);
        if (k2 + 8 <= NL) r1 = *(const float4*)(rp + k2 + 4);
        bx1.u[0] = packbf(r0.x, r0.y); bx1.u[1] = packbf(r0.z, r0.w);
        bx1.u[2] = packbf(r1.x, r1.y); bx1.u[3] = packbf(r1.z, r1.w);
      }
    }

    f32x16 acc = zero16();
    acc = __builtin_amdgcn_mfma_f32_32x32x16_bf16(ldsA(s_w, 0*4+s, l31, hi, 0), bx0.v, acc, 0, 0, 0);
    if (NL > 16)
      acc = __builtin_amdgcn_mfma_f32_32x32x16_bf16(ldsA(s_w, 0*4+s, l31, hi, 1), bx1.v, acc, 0, 0, 0);
    bf16x8 b0, b1;
    transition(acc, hi, b0, b1);
    acc = zero16();
    acc = __builtin_amdgcn_mfma_f32_32x32x16_bf16(ldsA(s_w, 4+s, l31, hi, 0), b0, acc, 0, 0, 0);
    acc = __builtin_amdgcn_mfma_f32_32x32x16_bf16(ldsA(s_w, 4+s, l31, hi, 1), b1, acc, 0, 0, 0);
    transition(acc, hi, b0, b1);
    acc = zero16();
    acc = __builtin_amdgcn_mfma_f32_32x32x16_bf16(ldsA(s_w, 8+s, l31, hi, 0), b0, acc, 0, 0, 0);
    acc = __builtin_amdgcn_mfma_f32_32x32x16_bf16(ldsA(s_w, 8+s, l31, hi, 1), b1, acc, 0, 0, 0);
    transition(acc, hi, b0, b1);
    acc = zero16();
    acc = __builtin_amdgcn_mfma_f32_32x32x16_bf16(ldsA(s_w, 12+s, l31, hi, 0), b0, acc, 0, 0, 0);
    acc = __builtin_amdgcn_mfma_f32_32x32x16_bf16(ldsA(s_w, 12+s, l31, hi, 1), b1, acc, 0, 0, 0);

    // store: reg quad t -> jo = 8t + 4hi + 0..3 (contiguous, 16B aligned)
    if (l31 < gcnt) {
      float* op = out + (long)row * 72 + OFF;
      #pragma unroll
      for (int t = 0; t < 4; ++t) {
        if (8*t + 4*hi + 4 <= NL) {
          float4 v = make_float4(acc[4*t], acc[4*t+1], acc[4*t+2], acc[4*t+3]);
          *(float4*)(op + 8*t + 4*hi) = v;
        }
      }
    }
  }
}

__global__ __launch_bounds__(256, 3) void RadialBasis_51316269253437_kernel(
    const float* __restrict__ rad, const int* __restrict__ spc,
    Wptrs wp, float* __restrict__ out, int npairs)
{
  __shared__ unsigned short s_w[16*32*KP];   // 40 KB: 16 tiles [32][KP] bf16
  __shared__ unsigned short s_perm[1024];
  __shared__ int s_cnt[4], s_fill[4], s_off[4], s_gpre[5];
  const int tid = threadIdx.x;
  const int base = blockIdx.x << 10;
  int vb = npairs - base; if (vb > 1024) vb = 1024;

  if (tid < 4) { s_cnt[tid] = 0; s_fill[tid] = 0; }
  __syncthreads();
  int sps[4];
  #pragma unroll
  for (int t = 0; t < 4; ++t) {
    int i = t*256 + tid;
    int sp = -1;
    if (i < vb) sp = spc[base + i];
    sps[t] = sp;
    if (sp >= 0) atomicAdd(&s_cnt[sp], 1);
  }
  __syncthreads();
  if (tid == 0) {
    int o = 0, gp = 0;
    #pragma unroll
    for (int s4 = 0; s4 < 4; ++s4) {
      s_off[s4] = o; o += s_cnt[s4];
      s_gpre[s4] = gp; gp += (s_cnt[s4] + 31) >> 5;
    }
    s_gpre[4] = gp;
  }
  __syncthreads();
  #pragma unroll
  for (int t = 0; t < 4; ++t) {
    int sp = sps[t];
    if (sp >= 0) {
      int pos = s_off[sp] + atomicAdd(&s_fill[sp], 1);
      s_perm[pos] = (unsigned short)(t*256 + tid);
    }
  }
  // each phase begins with __syncthreads()
  phase<24,  0>(rad, out, wp.p[ 0], wp.p[ 1], wp.p[ 2], wp.p[ 3], s_w, s_perm, s_cnt, s_off, s_gpre, base, tid);
  phase<20, 24>(rad, out, wp.p[ 4], wp.p[ 5], wp.p[ 6], wp.p[ 7], s_w, s_perm, s_cnt, s_off, s_gpre, base, tid);
  phase<16, 44>(rad, out, wp.p[ 8], wp.p[ 9], wp.p[10], wp.p[11], s_w, s_perm, s_cnt, s_off, s_gpre, base, tid);
  phase<12, 60>(rad, out, wp.p[12], wp.p[13], wp.p[14], wp.p[15], s_w, s_perm, s_cnt, s_off, s_gpre, base, tid);
}

extern "C" void kernel_launch(void* const* d_in, const int* in_sizes, int n_in,
                              void* d_out, int out_size, void* d_ws, size_t ws_size,
                              hipStream_t stream) {
  const float* rad = (const float*)d_in[0];
  const int* spc  = (const int*)d_in[1];
  Wptrs wp;
  for (int i = 0; i < 16; ++i) wp.p[i] = (const float*)d_in[2 + i];
  float* out = (float*)d_out;
  int npairs = in_sizes[0] / 72;
  int grid = (npairs + 1023) >> 10;
  RadialBasis_51316269253437_kernel<<<dim3(grid), dim3(256), 0, stream>>>(rad, spc, wp, out, npairs);
}